// Round 2
// baseline (556.820 us; speedup 1.0000x reference)
//
#include <hip/hip_runtime.h>
#include <hip/hip_bf16.h>
#include <hip/hip_fp16.h>

#define B_ 8
#define S_ 2048
#define D_ 512

typedef _Float16 f16x8 __attribute__((ext_vector_type(8)));
typedef float f32x4 __attribute__((ext_vector_type(4)));

// async global->LDS, 16B per lane (HW: wave-uniform LDS base + lane*16)
__device__ __forceinline__ void gload16(const void* g, void* l) {
    __builtin_amdgcn_global_load_lds(
        (const __attribute__((address_space(1))) void*)g,
        (__attribute__((address_space(3))) void*)l, 16, 0, 0);
}

// ---------------------------------------------------------------------------
// Kernel 1: W (fp32 [k][n]) -> W^T (fp16 [n][k])
// ---------------------------------------------------------------------------
__global__ void wconv_kernel(const float* __restrict__ Wq,
                             const float* __restrict__ Wk,
                             const float* __restrict__ Wv,
                             _Float16* __restrict__ w_ws) {
    int idx = blockIdx.x * 256 + threadIdx.x;       // 0 .. 512*512-1
    int which = blockIdx.y;
    const float* W = (which == 0) ? Wq : (which == 1) ? Wk : Wv;
    int n = idx >> 9;
    int k = idx & 511;
    w_ws[(size_t)which * D_ * D_ + (size_t)n * D_ + k] = (_Float16)W[(size_t)k * D_ + n];
}

// ---------------------------------------------------------------------------
// Kernel 2: projection GEMM, m97-style: global_load_lds staging + MFMA.
// Tile 128x128, BK=32, 256 thr (4 waves). A fp32 (swizzled slots of 16B),
// B fp16 W^T (swizzled). v output stored transposed v_ws[b][d][s].
// ---------------------------------------------------------------------------
__launch_bounds__(256)
__global__ void proj_kernel(const float* __restrict__ Q,
                            const float* __restrict__ K,
                            const float* __restrict__ V,
                            const _Float16* __restrict__ w_ws,
                            const float* __restrict__ bq,
                            const float* __restrict__ bk,
                            const float* __restrict__ bv,
                            _Float16* __restrict__ q_ws,
                            _Float16* __restrict__ k_ws,
                            _Float16* __restrict__ v_ws) {
    __shared__ __align__(16) float    As[128 * 32];   // 16 KB, [row][8 slots of 4 f32]
    __shared__ __align__(16) _Float16 Bs[128 * 32];   // 8 KB,  [col][4 slots of 8 f16]

    const int which = blockIdx.z;
    const float* X    = (which == 0) ? Q  : (which == 1) ? K  : V;
    const float* bias = (which == 0) ? bq : (which == 1) ? bk : bv;
    const _Float16* Wt = w_ws + (size_t)which * D_ * D_;

    const int Nb = blockIdx.x * 128;   // x fastest: 4 Nb-blocks share the A-tile
    const int Mb = blockIdx.y * 128;
    const int t = threadIdx.x;
    const int w = t >> 6;
    const int l = t & 63;
    const int lr = l & 15;
    const int lk = (l >> 4) * 8;
    const int lq = (l >> 4) * 4;

    f32x4 acc[2][8] = {};

    for (int k0 = 0; k0 < D_; k0 += 32) {
        // stage A: 1024 chunks of 16B (4/thread). chunk c: row=c>>3, lds slot p=c&7
        // holds global slot p^(row&7)  (both-sides swizzle, m201 pattern)
        {
            int c = t;
#pragma unroll
            for (int i = 0; i < 4; i++, c += 256) {
                int row = c >> 3, p = c & 7;
                gload16(X + (size_t)(Mb + row) * D_ + k0 + ((p ^ (row & 7)) << 2),
                        As + c * 4);
            }
        }
        // stage B: 512 chunks (2/thread). chunk c: col=c>>2, slot p=c&3 holds p^(col&3)
        {
            int c = t;
#pragma unroll
            for (int i = 0; i < 2; i++, c += 256) {
                int col = c >> 2, p = c & 3;
                gload16(Wt + (size_t)(Nb + col) * D_ + k0 + ((p ^ (col & 3)) << 3),
                        Bs + c * 8);
            }
        }
        __syncthreads();   // staging complete (compiler drains vmcnt)

        f16x8 a[2], b[8];
#pragma unroll
        for (int mi = 0; mi < 2; mi++) {
            int row = w * 32 + mi * 16 + lr;
            int s0 = lk >> 2;                      // logical 16B slot (0,2,4,6)
            const float* base = As + row * 32;
            f32x4 a0 = *(const f32x4*)(base + ((s0 ^ (row & 7)) << 2));
            f32x4 a1 = *(const f32x4*)(base + (((s0 + 1) ^ (row & 7)) << 2));
#pragma unroll
            for (int j = 0; j < 4; j++) { a[mi][j] = (_Float16)a0[j]; a[mi][4 + j] = (_Float16)a1[j]; }
        }
#pragma unroll
        for (int ni = 0; ni < 8; ni++) {
            int col = ni * 16 + lr;
            int s = lk >> 3;                       // logical 16B slot (0..3)
            b[ni] = *(const f16x8*)(Bs + col * 32 + ((s ^ (col & 3)) << 3));
        }
#pragma unroll
        for (int mi = 0; mi < 2; mi++)
#pragma unroll
            for (int ni = 0; ni < 8; ni++)
                acc[mi][ni] = __builtin_amdgcn_mfma_f32_16x16x32_f16(a[mi], b[ni], acc[mi][ni], 0, 0, 0);
        __syncthreads();   // all reads done before next-tile overwrite
    }

    // epilogue: + bias, cast fp16, store (v transposed)
#pragma unroll
    for (int ni = 0; ni < 8; ni++) {
        int col = Nb + ni * 16 + lr;
        float bn = bias[col];
#pragma unroll
        for (int mi = 0; mi < 2; mi++) {
#pragma unroll
            for (int j = 0; j < 4; j++) {
                int row = Mb + w * 32 + mi * 16 + lq + j;
                float vv = acc[mi][ni][j] + bn;
                if (which == 0) {
                    q_ws[(size_t)row * D_ + col] = (_Float16)vv;
                } else if (which == 1) {
                    k_ws[(size_t)row * D_ + col] = (_Float16)vv;
                } else {
                    int bb = row >> 11, s = row & 2047;
                    v_ws[((size_t)bb * D_ + col) * S_ + s] = (_Float16)vv;
                }
            }
        }
    }
}

// ---------------------------------------------------------------------------
// Kernel 3: flash attention. QBLK=64, KVBLK=256, 1024 thr = 16 waves
// = 2 q-groups x 8 kv/d-chunks. 2 barriers per kv-tile, 8 tiles.
// ---------------------------------------------------------------------------
__launch_bounds__(1024)
__global__ void attn_kernel(const _Float16* __restrict__ q_ws,
                            const _Float16* __restrict__ k_ws,
                            const _Float16* __restrict__ v_ws,
                            float* __restrict__ out) {
    __shared__ float    S_lds[64][260];     // stride 1040B: float4 reads conflict-free
    __shared__ _Float16 P_lds[64][264];     // stride 528B: b128 reads ~2-way
    __shared__ float    m_lds[64];
    __shared__ float    l_lds[64];
    __shared__ float    alpha_lds[64];

    const int bid = blockIdx.x;
    const int b  = bid & 7;        // batch -> XCD affinity (K/V L2 residency)
    const int qb = (bid >> 3) * 64;

    const int t = threadIdx.x;
    const int w = t >> 6;          // wave 0..15
    const int l = t & 63;
    const int qg = w >> 3;         // 0..1 : q-row group (32 rows)
    const int kc = w & 7;          // 0..7 : kv-chunk (QK^T) / d-chunk (PV)
    const int lr = l & 15;
    const int lk = (l >> 4) * 8;
    const int lq = (l >> 4) * 4;

    const _Float16* qp = q_ws + (size_t)b * S_ * D_;
    const _Float16* kp = k_ws + (size_t)b * S_ * D_;
    const _Float16* vp = v_ws + (size_t)b * D_ * S_;

    if (t < 64) { m_lds[t] = -INFINITY; l_lds[t] = 0.f; }

    f32x4 oacc[2][4] = {};
    __syncthreads();

    for (int kv0 = 0; kv0 < S_; kv0 += 256) {
        // ---- QK^T: wave (qg,kc) computes S[qg*32..+32][kc*32..+32] over D=512
        f32x4 sacc[2][2] = {};
        for (int d0 = 0; d0 < D_; d0 += 32) {
            f16x8 aq[2], bk2[2];
#pragma unroll
            for (int mi = 0; mi < 2; mi++)
                aq[mi] = *(const f16x8*)(qp + (size_t)(qb + qg * 32 + mi * 16 + lr) * D_ + d0 + lk);
#pragma unroll
            for (int ni = 0; ni < 2; ni++)
                bk2[ni] = *(const f16x8*)(kp + (size_t)(kv0 + kc * 32 + ni * 16 + lr) * D_ + d0 + lk);
#pragma unroll
            for (int mi = 0; mi < 2; mi++)
#pragma unroll
                for (int ni = 0; ni < 2; ni++)
                    sacc[mi][ni] = __builtin_amdgcn_mfma_f32_16x16x32_f16(aq[mi], bk2[ni], sacc[mi][ni], 0, 0, 0);
        }
#pragma unroll
        for (int mi = 0; mi < 2; mi++)
#pragma unroll
            for (int ni = 0; ni < 2; ni++)
#pragma unroll
                for (int j = 0; j < 4; j++)
                    S_lds[qg * 32 + mi * 16 + lq + j][kc * 32 + ni * 16 + lr] = sacc[mi][ni][j];
        __syncthreads();

        // ---- online softmax: 16 threads per row (64 rows x 256 cols)
        {
            const int r = t >> 4;
            const int cs = (t & 15) * 16;
            float sv[16];
#pragma unroll
            for (int c4 = 0; c4 < 4; c4++)
                *(float4*)&sv[c4 * 4] = *(const float4*)&S_lds[r][cs + c4 * 4];
            float mx = sv[0];
#pragma unroll
            for (int c = 1; c < 16; c++) mx = fmaxf(mx, sv[c]);
            mx = fmaxf(mx, __shfl_xor(mx, 1));
            mx = fmaxf(mx, __shfl_xor(mx, 2));
            mx = fmaxf(mx, __shfl_xor(mx, 4));
            mx = fmaxf(mx, __shfl_xor(mx, 8));
            float m_old = m_lds[r];
            float m_new = fmaxf(m_old, mx);
            float ps = 0.f;
            f16x8 p0, p1;
#pragma unroll
            for (int c = 0; c < 8; c++) {
                float p = __expf(sv[c] - m_new);
                ps += p;
                p0[c] = (_Float16)p;
            }
#pragma unroll
            for (int c = 0; c < 8; c++) {
                float p = __expf(sv[c + 8] - m_new);
                ps += p;
                p1[c] = (_Float16)p;
            }
            *(f16x8*)&P_lds[r][cs]     = p0;
            *(f16x8*)&P_lds[r][cs + 8] = p1;
            ps += __shfl_xor(ps, 1);
            ps += __shfl_xor(ps, 2);
            ps += __shfl_xor(ps, 4);
            ps += __shfl_xor(ps, 8);
            if ((t & 15) == 0) {
                float al = __expf(m_old - m_new);
                alpha_lds[r] = al;
                l_lds[r] = l_lds[r] * al + ps;
                m_lds[r] = m_new;
            }
        }
        __syncthreads();

        // ---- rescale O, then PV: wave (qg,kc) owns d-cols kc*64..+64
#pragma unroll
        for (int mi = 0; mi < 2; mi++)
#pragma unroll
            for (int j = 0; j < 4; j++) {
                float al = alpha_lds[qg * 32 + mi * 16 + lq + j];
#pragma unroll
                for (int ni = 0; ni < 4; ni++) oacc[mi][ni][j] *= al;
            }

        for (int ks = 0; ks < 8; ks++) {
            f16x8 pa[2], vb[4];
#pragma unroll
            for (int mi = 0; mi < 2; mi++)
                pa[mi] = *(const f16x8*)&P_lds[qg * 32 + mi * 16 + lr][ks * 32 + lk];
#pragma unroll
            for (int ni = 0; ni < 4; ni++)
                vb[ni] = *(const f16x8*)(vp + (size_t)(kc * 64 + ni * 16 + lr) * S_ + kv0 + ks * 32 + lk);
#pragma unroll
            for (int mi = 0; mi < 2; mi++)
#pragma unroll
                for (int ni = 0; ni < 4; ni++)
                    oacc[mi][ni] = __builtin_amdgcn_mfma_f32_16x16x32_f16(pa[mi], vb[ni], oacc[mi][ni], 0, 0, 0);
        }
        // no barrier needed here: next S_lds write races nothing (softmax's
        // S-reads ended before the post-softmax barrier; PV touches only P_lds,
        // which next gets written only after the next post-QK^T barrier)
    }

    // ---- normalize and store fp32 output
#pragma unroll
    for (int mi = 0; mi < 2; mi++)
#pragma unroll
        for (int j = 0; j < 4; j++) {
            int row = qg * 32 + mi * 16 + lq + j;
            float rl = 1.f / l_lds[row];
#pragma unroll
            for (int ni = 0; ni < 4; ni++) {
                int col = kc * 64 + ni * 16 + lr;
                out[((size_t)b * S_ + qb + row) * D_ + col] = oacc[mi][ni][j] * rl;
            }
        }
}

// ---------------------------------------------------------------------------
extern "C" void kernel_launch(void* const* d_in, const int* in_sizes, int n_in,
                              void* d_out, int out_size, void* d_ws, size_t ws_size,
                              hipStream_t stream) {
    const float* Q  = (const float*)d_in[0];
    const float* K  = (const float*)d_in[1];
    const float* V  = (const float*)d_in[2];
    const float* Wq = (const float*)d_in[3];
    const float* bq = (const float*)d_in[4];
    const float* Wk = (const float*)d_in[5];
    const float* bk = (const float*)d_in[6];
    const float* Wv = (const float*)d_in[7];
    const float* bv = (const float*)d_in[8];
    float* out = (float*)d_out;

    char* ws = (char*)d_ws;
    _Float16* w_ws = (_Float16*)ws;                                  // 3*512*512
    _Float16* q_ws = (_Float16*)(ws + 3ull * 512 * 512 * 2);         // [8][2048][512]
    _Float16* k_ws = q_ws + 8ull * 2048 * 512;                       // [8][2048][512]
    _Float16* v_ws = k_ws + 8ull * 2048 * 512;                       // [8][512][2048] (transposed)

    wconv_kernel<<<dim3(1024, 3), 256, 0, stream>>>(Wq, Wk, Wv, w_ws);
    proj_kernel<<<dim3(4, 128, 3), 256, 0, stream>>>(Q, K, V, w_ws, bq, bk, bv, q_ws, k_ws, v_ws);
    attn_kernel<<<dim3(256), 1024, 0, stream>>>(q_ws, k_ws, v_ws, out);
}

// Round 3
// 449.398 us; speedup vs baseline: 1.2390x; 1.2390x over previous
//
#include <hip/hip_runtime.h>
#include <hip/hip_bf16.h>
#include <hip/hip_fp16.h>

#define B_ 8
#define S_ 2048
#define D_ 512

typedef _Float16 f16x8 __attribute__((ext_vector_type(8)));
typedef float f32x4 __attribute__((ext_vector_type(4)));

// async global->LDS, 16B per lane (HW: wave-uniform LDS base + lane*16)
__device__ __forceinline__ void gload16(const void* g, void* l) {
    __builtin_amdgcn_global_load_lds(
        (const __attribute__((address_space(1))) void*)g,
        (__attribute__((address_space(3))) void*)l, 16, 0, 0);
}

// ---------------------------------------------------------------------------
// Kernel 1: W (fp32 [k][n]) -> W^T (fp16 [n][k])
// ---------------------------------------------------------------------------
__global__ void wconv_kernel(const float* __restrict__ Wq,
                             const float* __restrict__ Wk,
                             const float* __restrict__ Wv,
                             _Float16* __restrict__ w_ws) {
    int idx = blockIdx.x * 256 + threadIdx.x;       // 0 .. 512*512-1
    int which = blockIdx.y;
    const float* W = (which == 0) ? Wq : (which == 1) ? Wk : Wv;
    int n = idx >> 9;
    int k = idx & 511;
    w_ws[(size_t)which * D_ * D_ + (size_t)n * D_ + k] = (_Float16)W[(size_t)k * D_ + n];
}

// ---------------------------------------------------------------------------
// Kernel 2: projection GEMM (m97-style LDS staging), tile 128x128, BK=32.
// v output stored transposed v_ws[b][d][s].
// ---------------------------------------------------------------------------
__launch_bounds__(256)
__global__ void proj_kernel(const float* __restrict__ Q,
                            const float* __restrict__ K,
                            const float* __restrict__ V,
                            const _Float16* __restrict__ w_ws,
                            const float* __restrict__ bq,
                            const float* __restrict__ bk,
                            const float* __restrict__ bv,
                            _Float16* __restrict__ q_ws,
                            _Float16* __restrict__ k_ws,
                            _Float16* __restrict__ v_ws) {
    __shared__ __align__(16) float    As[128 * 32];   // 16 KB
    __shared__ __align__(16) _Float16 Bs[128 * 32];   // 8 KB

    const int which = blockIdx.z;
    const float* X    = (which == 0) ? Q  : (which == 1) ? K  : V;
    const float* bias = (which == 0) ? bq : (which == 1) ? bk : bv;
    const _Float16* Wt = w_ws + (size_t)which * D_ * D_;

    const int Nb = blockIdx.x * 128;   // x fastest: 4 Nb-blocks share the A-tile
    const int Mb = blockIdx.y * 128;
    const int t = threadIdx.x;
    const int w = t >> 6;
    const int l = t & 63;
    const int lr = l & 15;
    const int lk = (l >> 4) * 8;
    const int lq = (l >> 4) * 4;

    f32x4 acc[2][8] = {};

    for (int k0 = 0; k0 < D_; k0 += 32) {
        {
            int c = t;
#pragma unroll
            for (int i = 0; i < 4; i++, c += 256) {
                int row = c >> 3, p = c & 7;
                gload16(X + (size_t)(Mb + row) * D_ + k0 + ((p ^ (row & 7)) << 2),
                        As + c * 4);
            }
        }
        {
            int c = t;
#pragma unroll
            for (int i = 0; i < 2; i++, c += 256) {
                int col = c >> 2, p = c & 3;
                gload16(Wt + (size_t)(Nb + col) * D_ + k0 + ((p ^ (col & 3)) << 3),
                        Bs + c * 8);
            }
        }
        __syncthreads();

        f16x8 a[2], b[8];
#pragma unroll
        for (int mi = 0; mi < 2; mi++) {
            int row = w * 32 + mi * 16 + lr;
            int s0 = lk >> 2;
            const float* base = As + row * 32;
            f32x4 a0 = *(const f32x4*)(base + ((s0 ^ (row & 7)) << 2));
            f32x4 a1 = *(const f32x4*)(base + (((s0 + 1) ^ (row & 7)) << 2));
#pragma unroll
            for (int j = 0; j < 4; j++) { a[mi][j] = (_Float16)a0[j]; a[mi][4 + j] = (_Float16)a1[j]; }
        }
#pragma unroll
        for (int ni = 0; ni < 8; ni++) {
            int col = ni * 16 + lr;
            int s = lk >> 3;
            b[ni] = *(const f16x8*)(Bs + col * 32 + ((s ^ (col & 3)) << 3));
        }
#pragma unroll
        for (int mi = 0; mi < 2; mi++)
#pragma unroll
            for (int ni = 0; ni < 8; ni++)
                acc[mi][ni] = __builtin_amdgcn_mfma_f32_16x16x32_f16(a[mi], b[ni], acc[mi][ni], 0, 0, 0);
        __syncthreads();
    }

#pragma unroll
    for (int ni = 0; ni < 8; ni++) {
        int col = Nb + ni * 16 + lr;
        float bn = bias[col];
#pragma unroll
        for (int mi = 0; mi < 2; mi++) {
#pragma unroll
            for (int j = 0; j < 4; j++) {
                int row = Mb + w * 32 + mi * 16 + lq + j;
                float vv = acc[mi][ni][j] + bn;
                if (which == 0) {
                    q_ws[(size_t)row * D_ + col] = (_Float16)vv;
                } else if (which == 1) {
                    k_ws[(size_t)row * D_ + col] = (_Float16)vv;
                } else {
                    int bb = row >> 11, s = row & 2047;
                    v_ws[((size_t)bb * D_ + col) * S_ + s] = (_Float16)vv;
                }
            }
        }
    }
}

// ---------------------------------------------------------------------------
// Kernel 3: flash attention. QBLK=32, KVBLK=256, 512 thr = 8 waves.
// Q staged once in fragment-packed LDS; waves split kv 8-way (QK^T) and
// d 8-way (PV). P (fp16) aliased into upper bytes of S rows (LDS diet ->
// 66 KB -> 2 blocks/CU). Grid 512 = 2 blocks/CU, 16 waves/CU.
// ---------------------------------------------------------------------------
__launch_bounds__(512, 4)
__global__ void attn_kernel(const _Float16* __restrict__ q_ws,
                            const _Float16* __restrict__ k_ws,
                            const _Float16* __restrict__ v_ws,
                            float* __restrict__ out) {
    // S row = 260 f32 = 1040 B. Cols 0..255 hold S (f32). P (fp16) aliased at
    // row bytes 528..1040 (written only by the row's own wave after its reads).
    __shared__ __align__(16) float    S_lds[32][260];   // 33.25 KB
    __shared__ __align__(16) _Float16 Q_lds[16384];     // 32 KB frag-packed
    __shared__ float m_lds[32];
    __shared__ float l_lds[32];
    __shared__ float alpha_lds[32];

    const int bid = blockIdx.x;
    const int b  = bid & 7;        // batch == XCD (round-robin dispatch)
    const int qb = (bid >> 3) * 32;

    const int t = threadIdx.x;
    const int w = t >> 6;          // wave 0..7
    const int l = t & 63;
    const int kc = w;              // kv-chunk (QK^T) / d-chunk (PV)
    const int lr = l & 15;
    const int lk = (l >> 4) * 8;
    const int lq = (l >> 4) * 4;

    const _Float16* qp = q_ws + (size_t)b * S_ * D_;
    const _Float16* kp = k_ws + (size_t)b * S_ * D_;
    const _Float16* vp = v_ws + (size_t)b * D_ * S_;

    // ---- stage Q fragments once: pair pi = ds*2+mi -> 64 lanes x 16B
#pragma unroll
    for (int i = 0; i < 4; i++) {
        int pi = w * 4 + i;
        int ds = pi >> 1, mi = pi & 1;
        gload16(qp + (size_t)(qb + mi * 16 + lr) * D_ + ds * 32 + lk,
                Q_lds + pi * 512 + l * 8);
    }
    if (t < 32) { m_lds[t] = -INFINITY; l_lds[t] = 0.f; }

    f32x4 oacc[2][4] = {};
    __syncthreads();

    for (int kv0 = 0; kv0 < S_; kv0 += 256) {
        // ---- QK^T: wave kc computes S[0..32][kc*32..+32] over D=512
        f32x4 sacc[2][2] = {};
#pragma unroll 4
        for (int d0 = 0; d0 < D_; d0 += 32) {
            int ds = d0 >> 5;
            f16x8 aq[2], bk2[2];
#pragma unroll
            for (int mi = 0; mi < 2; mi++)
                aq[mi] = *(const f16x8*)(Q_lds + (ds * 2 + mi) * 512 + l * 8);
#pragma unroll
            for (int ni = 0; ni < 2; ni++)
                bk2[ni] = *(const f16x8*)(kp + (size_t)(kv0 + kc * 32 + ni * 16 + lr) * D_ + d0 + lk);
#pragma unroll
            for (int mi = 0; mi < 2; mi++)
#pragma unroll
                for (int ni = 0; ni < 2; ni++)
                    sacc[mi][ni] = __builtin_amdgcn_mfma_f32_16x16x32_f16(aq[mi], bk2[ni], sacc[mi][ni], 0, 0, 0);
        }
#pragma unroll
        for (int mi = 0; mi < 2; mi++)
#pragma unroll
            for (int ni = 0; ni < 2; ni++)
#pragma unroll
                for (int j = 0; j < 4; j++)
                    S_lds[mi * 16 + lq + j][kc * 32 + ni * 16 + lr] = sacc[mi][ni][j];
        __syncthreads();

        // ---- online softmax: 16 threads per row (32 rows x 256 cols)
        {
            const int r = t >> 4;
            const int cs = (t & 15) * 16;
            float sv[16];
#pragma unroll
            for (int c4 = 0; c4 < 4; c4++)
                *(float4*)&sv[c4 * 4] = *(const float4*)&S_lds[r][cs + c4 * 4];
            float mx = sv[0];
#pragma unroll
            for (int c = 1; c < 16; c++) mx = fmaxf(mx, sv[c]);
            mx = fmaxf(mx, __shfl_xor(mx, 1));
            mx = fmaxf(mx, __shfl_xor(mx, 2));
            mx = fmaxf(mx, __shfl_xor(mx, 4));
            mx = fmaxf(mx, __shfl_xor(mx, 8));
            float m_old = m_lds[r];
            float m_new = fmaxf(m_old, mx);
            float ps = 0.f;
            f16x8 p0, p1;
#pragma unroll
            for (int c = 0; c < 8; c++) {
                float p = __expf(sv[c] - m_new);
                ps += p;
                p0[c] = (_Float16)p;
            }
#pragma unroll
            for (int c = 0; c < 8; c++) {
                float p = __expf(sv[c + 8] - m_new);
                ps += p;
                p1[c] = (_Float16)p;
            }
            // P alias: row r bytes 528.. of S row (same-wave read-before-write)
            char* prow = (char*)&S_lds[r][0] + 528;
            *(f16x8*)(prow + cs * 2)      = p0;
            *(f16x8*)(prow + cs * 2 + 16) = p1;
            ps += __shfl_xor(ps, 1);
            ps += __shfl_xor(ps, 2);
            ps += __shfl_xor(ps, 4);
            ps += __shfl_xor(ps, 8);
            if ((t & 15) == 0) {
                float al = __expf(m_old - m_new);
                alpha_lds[r] = al;
                l_lds[r] = l_lds[r] * al + ps;
                m_lds[r] = m_new;
            }
        }
        __syncthreads();

        // ---- rescale O, then PV: wave kc owns d-cols kc*64..+64
#pragma unroll
        for (int mi = 0; mi < 2; mi++)
#pragma unroll
            for (int j = 0; j < 4; j++) {
                float al = alpha_lds[mi * 16 + lq + j];
#pragma unroll
                for (int ni = 0; ni < 4; ni++) oacc[mi][ni][j] *= al;
            }

#pragma unroll 2
        for (int ks = 0; ks < 8; ks++) {
            f16x8 pa[2], vb[4];
#pragma unroll
            for (int mi = 0; mi < 2; mi++)
                pa[mi] = *(const f16x8*)((const char*)&S_lds[mi * 16 + lr][0] + 528 + (ks * 32 + lk) * 2);
#pragma unroll
            for (int ni = 0; ni < 4; ni++)
                vb[ni] = *(const f16x8*)(vp + (size_t)(kc * 64 + ni * 16 + lr) * S_ + kv0 + ks * 32 + lk);
#pragma unroll
            for (int mi = 0; mi < 2; mi++)
#pragma unroll
                for (int ni = 0; ni < 4; ni++)
                    oacc[mi][ni] = __builtin_amdgcn_mfma_f32_16x16x32_f16(pa[mi], vb[ni], oacc[mi][ni], 0, 0, 0);
        }
        __syncthreads();   // P (aliased in S) must be fully read before next S write
    }

    // ---- normalize and store fp32 output
#pragma unroll
    for (int mi = 0; mi < 2; mi++)
#pragma unroll
        for (int j = 0; j < 4; j++) {
            int row = mi * 16 + lq + j;
            float rl = 1.f / l_lds[row];
#pragma unroll
            for (int ni = 0; ni < 4; ni++) {
                int col = kc * 64 + ni * 16 + lr;
                out[((size_t)b * S_ + qb + row) * D_ + col] = oacc[mi][ni][j] * rl;
            }
        }
}

// ---------------------------------------------------------------------------
extern "C" void kernel_launch(void* const* d_in, const int* in_sizes, int n_in,
                              void* d_out, int out_size, void* d_ws, size_t ws_size,
                              hipStream_t stream) {
    const float* Q  = (const float*)d_in[0];
    const float* K  = (const float*)d_in[1];
    const float* V  = (const float*)d_in[2];
    const float* Wq = (const float*)d_in[3];
    const float* bq = (const float*)d_in[4];
    const float* Wk = (const float*)d_in[5];
    const float* bk = (const float*)d_in[6];
    const float* Wv = (const float*)d_in[7];
    const float* bv = (const float*)d_in[8];
    float* out = (float*)d_out;

    char* ws = (char*)d_ws;
    _Float16* w_ws = (_Float16*)ws;                                  // 3*512*512
    _Float16* q_ws = (_Float16*)(ws + 3ull * 512 * 512 * 2);         // [8][2048][512]
    _Float16* k_ws = q_ws + 8ull * 2048 * 512;                       // [8][2048][512]
    _Float16* v_ws = k_ws + 8ull * 2048 * 512;                       // [8][512][2048] (transposed)

    wconv_kernel<<<dim3(1024, 3), 256, 0, stream>>>(Wq, Wk, Wv, w_ws);
    proj_kernel<<<dim3(4, 128, 3), 256, 0, stream>>>(Q, K, V, w_ws, bq, bk, bv, q_ws, k_ws, v_ws);
    attn_kernel<<<dim3(512), 512, 0, stream>>>(q_ws, k_ws, v_ws, out);
}